// Round 19
// baseline (411.012 us; speedup 1.0000x reference)
//
#include <hip/hip_runtime.h>
#include <hip/hip_bf16.h>

// ---------------------------------------------------------------------------
// Decoder_SICA — ROUND 18: asymmetric mf-trim (upper-M waves compute 3 tiles,
// not 4 — rows 100..127 were pure discard). Rest = r17 (verified).
// ---------------------------------------------------------------------------

typedef __attribute__((ext_vector_type(8))) short bf16x8;
typedef __attribute__((ext_vector_type(4))) float f32x4;

__device__ __forceinline__ short round_bf16(float v) {
    __hip_bfloat16 h = __float2bfloat16(v);
    return __builtin_bit_cast(short, h);
}

__device__ __forceinline__ int xcd_swizzle(int bid, int total) {
    int q = total >> 3, r = total & 7;
    int xcd = bid & 7, idx = bid >> 3;
    return (xcd < r ? xcd * (q + 1) : r * (q + 1) + (xcd - r) * q) + idx;
}

// zero only the border cells of padded NHWC planes [Bc][HP][HP][C]
template<int HP, int C>
__global__ void zero_border(short* __restrict__ p, int Bc)
{
    constexpr int NB = 2 * HP + 2 * (HP - 2);
    constexpr int C8 = C / 8;
    int idx = blockIdx.x * blockDim.x + threadIdx.x;
    int total = Bc * NB * C8;
    if (idx >= total) return;
    int c8 = idx % C8;
    int t  = idx / C8;
    int pb = t % NB;
    int b  = t / NB;
    int r, c;
    if (pb < HP)          { r = 0;      c = pb; }
    else if (pb < 2 * HP) { r = HP - 1; c = pb - HP; }
    else { int s = pb - 2 * HP; r = 1 + (s >> 1); c = (s & 1) ? HP - 1 : 0; }
    size_t d = (((size_t)b * HP + r) * HP + c) * C + c8 * 8;
    *(bf16x8*)&p[d] = (bf16x8){0, 0, 0, 0, 0, 0, 0, 0};
}

// W (OC,384,3,3) fp32 -> bf16 frag order [oc/16][s=t*12+ic/32][lane][8], 8/thread
__global__ void pack_w_frag_h8(const float* __restrict__ W,
                               short* __restrict__ wh, int total8)
{
    int idx = blockIdx.x * blockDim.x + threadIdx.x;
    if (idx >= total8) return;
    int oc = idx / 432, r = idx - oc * 432;     // 3456/8 = 432
    int t = r / 48, ic8 = r - t * 48;
    int ic = ic8 * 8;
    bf16x8 out;
    #pragma unroll
    for (int e = 0; e < 8; ++e)
        out[e] = round_bf16(W[((size_t)oc * 384 + ic + e) * 9 + t]);
    int g16 = oc >> 4, l15 = oc & 15;
    int c = ic >> 5, kg = (ic >> 3) & 3;
    size_t d = (((size_t)g16 * 108 + (t * 12 + c)) * 64 + kg * 16 + l15) * 8;
    *(bf16x8*)&wh[d] = out;
}

// W4 (512,12800) fp32 -> bf16 [oc/16][s=k/32][lane][8], 8/thread (float4 reads)
__global__ void pack_w4_frag_h8(const float* __restrict__ W,
                                short* __restrict__ wh, int total8)
{
    int idx = blockIdx.x * blockDim.x + threadIdx.x;
    if (idx >= total8) return;
    int oc = idx / 1600, k8 = idx - oc * 1600;
    int k = k8 * 8;
    const float4 f0 = *(const float4*)&W[(size_t)oc * 12800 + k];
    const float4 f1 = *(const float4*)&W[(size_t)oc * 12800 + k + 4];
    bf16x8 out;
    out[0] = round_bf16(f0.x); out[1] = round_bf16(f0.y);
    out[2] = round_bf16(f0.z); out[3] = round_bf16(f0.w);
    out[4] = round_bf16(f1.x); out[5] = round_bf16(f1.y);
    out[6] = round_bf16(f1.z); out[7] = round_bf16(f1.w);
    int g16 = oc >> 4, l15 = oc & 15;
    int s = k >> 5, kg = (k >> 3) & 3;
    size_t d = (((size_t)g16 * 400 + s) * 64 + kg * 16 + l15) * 8;
    *(bf16x8*)&wh[d] = out;
}

// einsum -> padded NHWC bf16 plane x0[b][12][12][384], interior only.
__global__ void __launch_bounds__(384)
einsum_pack3(const float* __restrict__ A, const float* __restrict__ S,
             short* __restrict__ oh)
{
    __shared__ float sS[4800];
    const int b  = blockIdx.x;
    const int ch = threadIdx.x;

    const float4* S4 = (const float4*)(S + (size_t)b * 4800);
    for (int i = threadIdx.x; i < 1200; i += 384)
        ((float4*)sS)[i] = S4[i];

    const int n = ch / 48, rr = ch - n * 48;
    const int g = rr / 3,  o = rr - g * 3;

    const float4* A4 = (const float4*)(A + (size_t)b * 2048) + (n * 64 + g * 4);
    float4 av0 = A4[0], av1 = A4[1], av2 = A4[2], av3 = A4[3];

    __syncthreads();

    const float* Sb = sS + g * 300 + o * 25;

    #pragma unroll
    for (int h = 0; h < 2; ++h) {
        #pragma unroll
        for (int w = 0; w < 2; ++w) {
            const float a0 = (h == 0 && w == 0) ? av0.x : (h == 0 && w == 1) ? av0.y
                           : (h == 1 && w == 0) ? av0.z : av0.w;
            const float a1 = (h == 0 && w == 0) ? av1.x : (h == 0 && w == 1) ? av1.y
                           : (h == 1 && w == 0) ? av1.z : av1.w;
            const float a2 = (h == 0 && w == 0) ? av2.x : (h == 0 && w == 1) ? av2.y
                           : (h == 1 && w == 0) ? av2.z : av2.w;
            const float a3 = (h == 0 && w == 0) ? av3.x : (h == 0 && w == 1) ? av3.y
                           : (h == 1 && w == 0) ? av3.z : av3.w;
            size_t dbase = ((size_t)(b * 12 + h * 5 + 1) * 12 + (w * 5 + 1)) * 384 + ch;
            #pragma unroll
            for (int pp = 0; pp < 5; ++pp) {
                #pragma unroll
                for (int q = 0; q < 5; ++q) {
                    const int soff = pp * 5 + q;
                    float s = a0 * Sb[soff] + a1 * Sb[75 + soff]
                            + a2 * Sb[150 + soff] + a3 * Sb[225 + soff];
                    oh[dbase + (size_t)(pp * 12 + q) * 384] = round_bf16(s);
                }
            }
        }
    }
}

// Tap-stationary implicit-GEMM 3x3 conv, pipelined chunk loop with
// cross-chunk B prefetch and asymmetric mf-trim (no wasted M-pad MFMA).
template<int OC_T, int HOUT, int HPIN, int HPOUT, int STRIDE, int MODE, int NT,
         int NSAMP, int DBUF>
__global__ void __launch_bounds__(256)
conv_mfma5(const short* __restrict__ in_h, const short* __restrict__ wph,
           const float* __restrict__ bias, short* __restrict__ out_h)
{
    constexpr int IC = 384;
    constexpr int NS = 108;
    constexpr int NF = NT / 32;
    constexpr int PIX = HOUT * HOUT;
    constexpr int M_BLK = NSAMP * PIX;
    constexpr int PROWS = NSAMP * HPIN * HPIN;
    constexpr int G = OC_T / NT;
    constexpr int NU = (PROWS * 2 + 255) / 256;
    constexpr int BUFSZ = PROWS * 40;
    __shared__ short s_a[(DBUF ? 2 : 1) * BUFSZ];

    const int swz = xcd_swizzle(blockIdx.x, gridDim.x);
    const int mt = swz / G;
    const int g  = swz % G;
    const int n0 = g * NT;
    const int bb0 = mt * NSAMP;

    const int tid = threadIdx.x;
    const int lane = tid & 63;
    const int wid  = tid >> 6;
    const int wm = (wid & 1) * 64;
    const int wn = (wid >> 1) * (NT / 2);
    const int l15 = lane & 15, kg = lane >> 4;

    // wave-uniform count of useful 16-row tiles for this wave's M range
    const int mrows = M_BLK - wm;                       // 100 or 36 (M_BLK=100)
    const int mfc = mrows >= 64 ? 4 : (mrows + 15) >> 4;

    size_t usrc[NU]; int udst[NU]; bool uval[NU];
    #pragma unroll
    for (int j = 0; j < NU; ++j) {
        int u = tid + j * 256;
        int row = u >> 1, hf = u & 1;
        uval[j] = row < PROWS;
        int rc = uval[j] ? row : 0;
        int sN = rc / (HPIN * HPIN), rr = rc % (HPIN * HPIN);
        usrc[j] = ((size_t)(bb0 + sN) * (HPIN * HPIN) + rr) * IC + hf * 16;
        udst[j] = rc * 40 + hf * 16;
    }

    int prow[4];
    #pragma unroll
    for (int mf = 0; mf < 4; ++mf) {
        int p = wm + mf * 16 + l15;
        int pc = p < M_BLK ? p : M_BLK - 1;
        int sN = pc / PIX, pr = pc % PIX;
        int py = pr / HOUT, px = pr - py * HOUT;
        prow[mf] = sN * (HPIN * HPIN) + py * STRIDE * HPIN + px * STRIDE;
    }

    const short* wb = wph + (size_t)((n0 + wn) >> 4) * (NS * 512) + lane * 8;

    f32x4 acc[4][NF];
    #pragma unroll
    for (int i = 0; i < 4; ++i)
        #pragma unroll
        for (int j = 0; j < NF; ++j)
            acc[i][j] = (f32x4){0.f, 0.f, 0.f, 0.f};

    bf16x8 sreg[NU][2];
    auto loadG = [&](int c) {
        #pragma unroll
        for (int j = 0; j < NU; ++j) if (uval[j]) {
            const short* src = in_h + usrc[j] + c * 32;
            sreg[j][0] = *(const bf16x8*)src;
            sreg[j][1] = *(const bf16x8*)(src + 8);
        }
    };
    auto writeL = [&](int off) {
        #pragma unroll
        for (int j = 0; j < NU; ++j) if (uval[j]) {
            *(bf16x8*)&s_a[off + udst[j]]     = sreg[j][0];
            *(bf16x8*)&s_a[off + udst[j] + 8] = sreg[j][1];
        }
    };
    auto loadB = [&](int s, bf16x8 (&bh)[NF]) {
        #pragma unroll
        for (int nf = 0; nf < NF; ++nf)
            bh[nf] = *(const bf16x8*)(wb + (size_t)nf * (NS * 512) + (size_t)s * 512);
    };
    // bcur must be pre-loaded with tap-0 of chunk c before calling.
    auto compute = [&](int c, int off, bf16x8 (&bcur)[NF]) {
        bf16x8 bnxt[NF];
        #pragma unroll
        for (int t = 0; t < 9; ++t) {
            const int sn = (t < 8) ? ((t + 1) * 12 + c) : (c < 11 ? (c + 1) : 0);
            loadB(sn, bnxt);
            const int troff = (t / 3) * HPIN + (t % 3);
            bf16x8 af[4];
            #pragma unroll
            for (int mf = 0; mf < 4; ++mf)
                if (mf < mfc)
                    af[mf] = *(const bf16x8*)&s_a[off + (prow[mf] + troff) * 40 + kg * 8];
            __builtin_amdgcn_s_setprio(1);
            #pragma unroll
            for (int nf = 0; nf < NF; ++nf)
                #pragma unroll
                for (int mf = 0; mf < 4; ++mf)
                    if (mf < mfc)
                        acc[mf][nf] = __builtin_amdgcn_mfma_f32_16x16x32_bf16(
                            af[mf], bcur[nf], acc[mf][nf], 0, 0, 0);
            __builtin_amdgcn_s_setprio(0);
            #pragma unroll
            for (int nf = 0; nf < NF; ++nf) bcur[nf] = bnxt[nf];
        }
    };

    bf16x8 bpipe[NF];
    loadB(0, bpipe);                             // tap-0, chunk-0

    if (DBUF) {
        loadG(0); writeL(0);
        __syncthreads();
        int buf = 0;
        for (int c = 0; c < 12; ++c) {
            if (c + 1 < 12) loadG(c + 1);
            compute(c, buf * BUFSZ, bpipe);
            if (c + 1 < 12) writeL((buf ^ 1) * BUFSZ);
            __syncthreads();
            buf ^= 1;
        }
    } else {
        loadG(0);
        for (int c = 0; c < 12; ++c) {
            if (c) __syncthreads();
            writeL(0);
            __syncthreads();
            if (c + 1 < 12) loadG(c + 1);
            compute(c, 0, bpipe);
        }
    }

    #pragma unroll
    for (int nf = 0; nf < NF; ++nf) {
        const int oc = n0 + wn + nf * 16 + l15;
        const float bv = bias[oc];
        #pragma unroll
        for (int mf = 0; mf < 4; ++mf) {
            #pragma unroll
            for (int j = 0; j < 4; ++j) {
                int p_out = wm + mf * 16 + kg * 4 + j;
                if (p_out < M_BLK) {
                    float v = acc[mf][nf][j] + bv;
                    v = v > 0.f ? v : 0.f;
                    int b2 = bb0 + p_out / PIX;
                    int pr2 = p_out % PIX;
                    if (MODE == 0) {
                        int y2 = pr2 / HOUT, x2 = pr2 - y2 * HOUT;
                        size_t d = ((size_t)(b2 * HPOUT + y2 + 1) * HPOUT + (x2 + 1)) * OC_T + oc;
                        out_h[d] = round_bf16(v);
                    } else {
                        out_h[((size_t)b2 * OC_T + oc) * PIX + pr2] = round_bf16(v);
                    }
                }
            }
        }
    }
}

// Split-K bf16 MFMA GEMM for conv4, single-product. KS=25 -> 16 k-steps.
template<int KS>
__global__ void __launch_bounds__(256)
gemm4_mfma3(const short* __restrict__ Ah, const short* __restrict__ wph,
            float* __restrict__ Cpart, int M)
{
    constexpr int NS4 = 400;
    constexpr int NSTEP = NS4 / KS;             // 16
    __shared__ short s_a[2][128 * 40];
    const int tid = threadIdx.x;
    const int nM = (M + 127) / 128;
    const int ks = blockIdx.x / (nM * 4);
    const int rb = blockIdx.x % (nM * 4);
    const int M0 = (rb / 4) * 128;
    const int n0 = (rb % 4) * 128;

    const int lane = tid & 63;
    const int wid  = tid >> 6;
    const int wm = (wid & 1) * 64;
    const int wn = (wid >> 1) * 64;
    const int l15 = lane & 15, kg = lane >> 4;

    const int arow = tid >> 1, ahf = tid & 1;
    int P = M0 + arow; if (P >= M) P = M - 1;
    const short* abase = Ah + (size_t)P * 12800 + ahf * 16;
    const int adst = arow * 40 + ahf * 16;

    const short* wbh = wph + (size_t)((n0 + wn) >> 4) * (NS4 * 512) + lane * 8;

    f32x4 acc[4][4];
    #pragma unroll
    for (int i = 0; i < 4; ++i)
        #pragma unroll
        for (int j = 0; j < 4; ++j)
            acc[i][j] = (f32x4){0.f, 0.f, 0.f, 0.f};

    auto stageA = [&](int j, int buf) {
        const short* src = abase + (size_t)(ks * NSTEP + j) * 32;
        *(bf16x8*)&s_a[buf][adst]     = *(const bf16x8*)src;
        *(bf16x8*)&s_a[buf][adst + 8] = *(const bf16x8*)(src + 8);
    };
    auto loadB = [&](int j, bf16x8 (&bh)[4]) {
        #pragma unroll
        for (int nf = 0; nf < 4; ++nf)
            bh[nf] = *(const bf16x8*)(wbh + (size_t)nf * (NS4 * 512)
                                      + (size_t)(ks * NSTEP + j) * 512);
    };
    auto compute = [&](const bf16x8 (&bh)[4], int buf) {
        bf16x8 af[4];
        #pragma unroll
        for (int mf = 0; mf < 4; ++mf)
            af[mf] = *(const bf16x8*)&s_a[buf][(wm + mf * 16 + l15) * 40 + kg * 8];
        __builtin_amdgcn_s_setprio(1);
        #pragma unroll
        for (int nf = 0; nf < 4; ++nf)
            #pragma unroll
            for (int mf = 0; mf < 4; ++mf)
                acc[mf][nf] = __builtin_amdgcn_mfma_f32_16x16x32_bf16(
                    af[mf], bh[nf], acc[mf][nf], 0, 0, 0);
        __builtin_amdgcn_s_setprio(0);
    };

    bf16x8 bhA[4], bhB[4];
    stageA(0, 0);
    loadB(0, bhA);
    __syncthreads();
    for (int jp = 0; jp < NSTEP; jp += 2) {
        stageA(jp + 1, 1);
        loadB(jp + 1, bhB);
        compute(bhA, 0);
        __syncthreads();
        if (jp + 2 < NSTEP) { stageA(jp + 2, 0); loadB(jp + 2, bhA); }
        compute(bhB, 1);
        __syncthreads();
    }

    float* cp = Cpart + (size_t)ks * M * 512;
    #pragma unroll
    for (int nf = 0; nf < 4; ++nf) {
        const int n = n0 + wn + nf * 16 + l15;
        #pragma unroll
        for (int mf = 0; mf < 4; ++mf) {
            #pragma unroll
            for (int j = 0; j < 4; ++j) {
                int m = M0 + wm + mf * 16 + kg * 4 + j;
                if (m < M) cp[(size_t)m * 512 + n] = acc[mf][nf][j];
            }
        }
    }
}

template<int KS>
__global__ void splitk_reduce_relu(const float* __restrict__ Cpart,
                                   const float* __restrict__ bias,
                                   float* __restrict__ out, int M, int N)
{
    int idx = blockIdx.x * blockDim.x + threadIdx.x;
    if (idx >= M * N) return;
    int oc = idx % N;
    float s = bias[oc];
    #pragma unroll
    for (int ks = 0; ks < KS; ++ks)
        s += Cpart[(size_t)ks * M * N + idx];
    out[idx] = s > 0.f ? s : 0.f;
}

__global__ void linear_naive(const float* __restrict__ x, const float* __restrict__ Wl,
                             const float* __restrict__ bl,
                             float* __restrict__ out, int total)
{
    int idx = blockIdx.x * blockDim.x + threadIdx.x;
    if (idx >= total) return;
    int b = idx / 10, j = idx - b * 10;
    const float* xb = x  + (size_t)b * 512;
    const float* wj = Wl + (size_t)j * 512;
    float s = bl[j];
    for (int k = 0; k < 512; ++k)
        s += xb[k] * wj[k];
    out[idx] = s;
}

extern "C" void kernel_launch(void* const* d_in, const int* in_sizes, int n_in,
                              void* d_out, int out_size, void* d_ws, size_t ws_size,
                              hipStream_t stream)
{
    const float* A  = (const float*)d_in[0];
    const float* S  = (const float*)d_in[1];
    const float* W1 = (const float*)d_in[2];
    const float* b1 = (const float*)d_in[3];
    const float* W2 = (const float*)d_in[4];
    const float* b2 = (const float*)d_in[5];
    const float* W3 = (const float*)d_in[6];
    const float* b3 = (const float*)d_in[7];
    const float* W4 = (const float*)d_in[8];
    const float* b4 = (const float*)d_in[9];
    const float* Wl = (const float*)d_in[10];
    const float* bl = (const float*)d_in[11];
    float* outp = (float*)d_out;
    char* base = (char*)d_ws;

    const int Btot = 512;
    constexpr int KS = 25;

    const size_t W12N = (size_t)384 * 3456;
    const size_t W3N  = (size_t)512 * 3456;
    const size_t W4N  = (size_t)512 * 12800;
    size_t off = 0;
    short* w1h = (short*)(base + off); off += W12N * 2;
    short* w2h = (short*)(base + off); off += W12N * 2;
    short* w3h = (short*)(base + off); off += W3N * 2;
    short* w4h = (short*)(base + off); off += W4N * 2;
    const size_t wreg = off;

    const size_t PS = 337664;
    int Bc = 512;
    while (Bc > 8 && wreg + (size_t)Bc * PS > ws_size) Bc >>= 1;

    pack_w_frag_h8<<<(int)((W12N / 8 + 255) / 256), 256, 0, stream>>>(W1, w1h, (int)(W12N / 8));
    pack_w_frag_h8<<<(int)((W12N / 8 + 255) / 256), 256, 0, stream>>>(W2, w2h, (int)(W12N / 8));
    pack_w_frag_h8<<<(int)((W3N  / 8 + 255) / 256), 256, 0, stream>>>(W3, w3h, (int)(W3N / 8));
    pack_w4_frag_h8<<<(int)((W4N / 8 + 255) / 256), 256, 0, stream>>>(W4, w4h, (int)(W4N / 8));

    size_t o2 = wreg;
    short* x0h = (short*)(base + o2); o2 += (size_t)Bc * 110592;
    short* x1h = (short*)(base + o2); o2 += (size_t)Bc * 110592;
    short* x2h = (short*)(base + o2); o2 += (size_t)Bc * 37632;
    short* x3h = (short*)(base + o2); o2 += (size_t)Bc * 25600;
    float* cp  = (float*)(base + o2); o2 += (size_t)Bc * (KS * 512 * 4);
    float* x4  = (float*)(base + o2);

    // border-only zeroing of padded planes (interiors rewritten every launch)
    {
        int t0 = Bc * 44 * 48;
        zero_border<12, 384><<<(t0 + 255) / 256, 256, 0, stream>>>(x0h, Bc);
        zero_border<12, 384><<<(t0 + 255) / 256, 256, 0, stream>>>(x1h, Bc);
        int t2 = Bc * 24 * 48;
        zero_border<7, 384><<<(t2 + 255) / 256, 256, 0, stream>>>(x2h, Bc);
    }

    for (int b0 = 0; b0 < Btot; b0 += Bc) {
        einsum_pack3<<<dim3(Bc), 384, 0, stream>>>(
            A + (size_t)b0 * 2048, S + (size_t)b0 * 4800, x0h);

        // conv1: 1 sample/block, NT=128, dbuf (LDS 23 KB), grid Bc*3
        conv_mfma5<384, 10, 12, 12, 1, 0, 128, 1, 1>
            <<<dim3(Bc * 3), 256, 0, stream>>>(x0h, w1h, b1, x1h);

        // conv2: 4 samples/block, NT=96 (G=4, NF=3), single-buf (46 KB)
        conv_mfma5<384, 5, 12, 7, 2, 0, 96, 4, 0>
            <<<dim3((Bc / 4) * 4), 256, 0, stream>>>(x1h, w2h, b2, x2h);

        // conv3: 4 samples/block, NT=128 (G=4), dbuf (31 KB), NCHW out
        conv_mfma5<512, 5, 7, 1, 1, 1, 128, 4, 1>
            <<<dim3((Bc / 4) * 4), 256, 0, stream>>>(x2h, w3h, b3, x3h);

        int nM = (Bc + 127) / 128;
        gemm4_mfma3<KS><<<dim3(KS * nM * 4), 256, 0, stream>>>(
            x3h, w4h, cp, Bc);
        int tr = Bc * 512;
        splitk_reduce_relu<KS><<<(tr + 255) / 256, 256, 0, stream>>>(
            cp, b4, x4, Bc, 512);

        int t5 = Bc * 10;
        linear_naive<<<(t5 + 255) / 256, 256, 0, stream>>>(
            x4, Wl, bl, outp + (size_t)b0 * 10, t5);
    }
}

// Round 20
// 405.665 us; speedup vs baseline: 1.0132x; 1.0132x over previous
//
#include <hip/hip_runtime.h>
#include <hip/hip_bf16.h>

// ---------------------------------------------------------------------------
// Decoder_SICA — ROUND 19: CP=2 conv phases (64 ic per barrier) for conv1
// (single-buf) and conv3 (dbuf). conv2 = r18 path. Rest verified earlier.
// ---------------------------------------------------------------------------

typedef __attribute__((ext_vector_type(8))) short bf16x8;
typedef __attribute__((ext_vector_type(4))) float f32x4;

__device__ __forceinline__ short round_bf16(float v) {
    __hip_bfloat16 h = __float2bfloat16(v);
    return __builtin_bit_cast(short, h);
}

__device__ __forceinline__ int xcd_swizzle(int bid, int total) {
    int q = total >> 3, r = total & 7;
    int xcd = bid & 7, idx = bid >> 3;
    return (xcd < r ? xcd * (q + 1) : r * (q + 1) + (xcd - r) * q) + idx;
}

// zero only the border cells of padded NHWC planes [Bc][HP][HP][C]
template<int HP, int C>
__global__ void zero_border(short* __restrict__ p, int Bc)
{
    constexpr int NB = 2 * HP + 2 * (HP - 2);
    constexpr int C8 = C / 8;
    int idx = blockIdx.x * blockDim.x + threadIdx.x;
    int total = Bc * NB * C8;
    if (idx >= total) return;
    int c8 = idx % C8;
    int t  = idx / C8;
    int pb = t % NB;
    int b  = t / NB;
    int r, c;
    if (pb < HP)          { r = 0;      c = pb; }
    else if (pb < 2 * HP) { r = HP - 1; c = pb - HP; }
    else { int s = pb - 2 * HP; r = 1 + (s >> 1); c = (s & 1) ? HP - 1 : 0; }
    size_t d = (((size_t)b * HP + r) * HP + c) * C + c8 * 8;
    *(bf16x8*)&p[d] = (bf16x8){0, 0, 0, 0, 0, 0, 0, 0};
}

// W (OC,384,3,3) fp32 -> bf16 frag order [oc/16][s=t*12+ic/32][lane][8], 8/thread
__global__ void pack_w_frag_h8(const float* __restrict__ W,
                               short* __restrict__ wh, int total8)
{
    int idx = blockIdx.x * blockDim.x + threadIdx.x;
    if (idx >= total8) return;
    int oc = idx / 432, r = idx - oc * 432;     // 3456/8 = 432
    int t = r / 48, ic8 = r - t * 48;
    int ic = ic8 * 8;
    bf16x8 out;
    #pragma unroll
    for (int e = 0; e < 8; ++e)
        out[e] = round_bf16(W[((size_t)oc * 384 + ic + e) * 9 + t]);
    int g16 = oc >> 4, l15 = oc & 15;
    int c = ic >> 5, kg = (ic >> 3) & 3;
    size_t d = (((size_t)g16 * 108 + (t * 12 + c)) * 64 + kg * 16 + l15) * 8;
    *(bf16x8*)&wh[d] = out;
}

// W4 (512,12800) fp32 -> bf16 [oc/16][s=k/32][lane][8], 8/thread (float4 reads)
__global__ void pack_w4_frag_h8(const float* __restrict__ W,
                                short* __restrict__ wh, int total8)
{
    int idx = blockIdx.x * blockDim.x + threadIdx.x;
    if (idx >= total8) return;
    int oc = idx / 1600, k8 = idx - oc * 1600;
    int k = k8 * 8;
    const float4 f0 = *(const float4*)&W[(size_t)oc * 12800 + k];
    const float4 f1 = *(const float4*)&W[(size_t)oc * 12800 + k + 4];
    bf16x8 out;
    out[0] = round_bf16(f0.x); out[1] = round_bf16(f0.y);
    out[2] = round_bf16(f0.z); out[3] = round_bf16(f0.w);
    out[4] = round_bf16(f1.x); out[5] = round_bf16(f1.y);
    out[6] = round_bf16(f1.z); out[7] = round_bf16(f1.w);
    int g16 = oc >> 4, l15 = oc & 15;
    int s = k >> 5, kg = (k >> 3) & 3;
    size_t d = (((size_t)g16 * 400 + s) * 64 + kg * 16 + l15) * 8;
    *(bf16x8*)&wh[d] = out;
}

// einsum -> padded NHWC bf16 plane x0[b][12][12][384], interior only.
__global__ void __launch_bounds__(384)
einsum_pack3(const float* __restrict__ A, const float* __restrict__ S,
             short* __restrict__ oh)
{
    __shared__ float sS[4800];
    const int b  = blockIdx.x;
    const int ch = threadIdx.x;

    const float4* S4 = (const float4*)(S + (size_t)b * 4800);
    for (int i = threadIdx.x; i < 1200; i += 384)
        ((float4*)sS)[i] = S4[i];

    const int n = ch / 48, rr = ch - n * 48;
    const int g = rr / 3,  o = rr - g * 3;

    const float4* A4 = (const float4*)(A + (size_t)b * 2048) + (n * 64 + g * 4);
    float4 av0 = A4[0], av1 = A4[1], av2 = A4[2], av3 = A4[3];

    __syncthreads();

    const float* Sb = sS + g * 300 + o * 25;

    #pragma unroll
    for (int h = 0; h < 2; ++h) {
        #pragma unroll
        for (int w = 0; w < 2; ++w) {
            const float a0 = (h == 0 && w == 0) ? av0.x : (h == 0 && w == 1) ? av0.y
                           : (h == 1 && w == 0) ? av0.z : av0.w;
            const float a1 = (h == 0 && w == 0) ? av1.x : (h == 0 && w == 1) ? av1.y
                           : (h == 1 && w == 0) ? av1.z : av1.w;
            const float a2 = (h == 0 && w == 0) ? av2.x : (h == 0 && w == 1) ? av2.y
                           : (h == 1 && w == 0) ? av2.z : av2.w;
            const float a3 = (h == 0 && w == 0) ? av3.x : (h == 0 && w == 1) ? av3.y
                           : (h == 1 && w == 0) ? av3.z : av3.w;
            size_t dbase = ((size_t)(b * 12 + h * 5 + 1) * 12 + (w * 5 + 1)) * 384 + ch;
            #pragma unroll
            for (int pp = 0; pp < 5; ++pp) {
                #pragma unroll
                for (int q = 0; q < 5; ++q) {
                    const int soff = pp * 5 + q;
                    float s = a0 * Sb[soff] + a1 * Sb[75 + soff]
                            + a2 * Sb[150 + soff] + a3 * Sb[225 + soff];
                    oh[dbase + (size_t)(pp * 12 + q) * 384] = round_bf16(s);
                }
            }
        }
    }
}

// --- r18 conv (CP=1) kept for conv2 ---
template<int OC_T, int HOUT, int HPIN, int HPOUT, int STRIDE, int MODE, int NT,
         int NSAMP, int DBUF>
__global__ void __launch_bounds__(256)
conv_mfma5(const short* __restrict__ in_h, const short* __restrict__ wph,
           const float* __restrict__ bias, short* __restrict__ out_h)
{
    constexpr int IC = 384;
    constexpr int NS = 108;
    constexpr int NF = NT / 32;
    constexpr int PIX = HOUT * HOUT;
    constexpr int M_BLK = NSAMP * PIX;
    constexpr int PROWS = NSAMP * HPIN * HPIN;
    constexpr int G = OC_T / NT;
    constexpr int NU = (PROWS * 2 + 255) / 256;
    constexpr int BUFSZ = PROWS * 40;
    __shared__ short s_a[(DBUF ? 2 : 1) * BUFSZ];

    const int swz = xcd_swizzle(blockIdx.x, gridDim.x);
    const int mt = swz / G;
    const int g  = swz % G;
    const int n0 = g * NT;
    const int bb0 = mt * NSAMP;

    const int tid = threadIdx.x;
    const int lane = tid & 63;
    const int wid  = tid >> 6;
    const int wm = (wid & 1) * 64;
    const int wn = (wid >> 1) * (NT / 2);
    const int l15 = lane & 15, kg = lane >> 4;

    const int mrows = M_BLK - wm;
    const int mfc = mrows >= 64 ? 4 : (mrows + 15) >> 4;

    size_t usrc[NU]; int udst[NU]; bool uval[NU];
    #pragma unroll
    for (int j = 0; j < NU; ++j) {
        int u = tid + j * 256;
        int row = u >> 1, hf = u & 1;
        uval[j] = row < PROWS;
        int rc = uval[j] ? row : 0;
        int sN = rc / (HPIN * HPIN), rr = rc % (HPIN * HPIN);
        usrc[j] = ((size_t)(bb0 + sN) * (HPIN * HPIN) + rr) * IC + hf * 16;
        udst[j] = rc * 40 + hf * 16;
    }

    int prow[4];
    #pragma unroll
    for (int mf = 0; mf < 4; ++mf) {
        int p = wm + mf * 16 + l15;
        int pc = p < M_BLK ? p : M_BLK - 1;
        int sN = pc / PIX, pr = pc % PIX;
        int py = pr / HOUT, px = pr - py * HOUT;
        prow[mf] = sN * (HPIN * HPIN) + py * STRIDE * HPIN + px * STRIDE;
    }

    const short* wb = wph + (size_t)((n0 + wn) >> 4) * (NS * 512) + lane * 8;

    f32x4 acc[4][NF];
    #pragma unroll
    for (int i = 0; i < 4; ++i)
        #pragma unroll
        for (int j = 0; j < NF; ++j)
            acc[i][j] = (f32x4){0.f, 0.f, 0.f, 0.f};

    bf16x8 sreg[NU][2];
    auto loadG = [&](int c) {
        #pragma unroll
        for (int j = 0; j < NU; ++j) if (uval[j]) {
            const short* src = in_h + usrc[j] + c * 32;
            sreg[j][0] = *(const bf16x8*)src;
            sreg[j][1] = *(const bf16x8*)(src + 8);
        }
    };
    auto writeL = [&](int off) {
        #pragma unroll
        for (int j = 0; j < NU; ++j) if (uval[j]) {
            *(bf16x8*)&s_a[off + udst[j]]     = sreg[j][0];
            *(bf16x8*)&s_a[off + udst[j] + 8] = sreg[j][1];
        }
    };
    auto loadB = [&](int s, bf16x8 (&bh)[NF]) {
        #pragma unroll
        for (int nf = 0; nf < NF; ++nf)
            bh[nf] = *(const bf16x8*)(wb + (size_t)nf * (NS * 512) + (size_t)s * 512);
    };
    auto compute = [&](int c, int off, bf16x8 (&bcur)[NF]) {
        bf16x8 bnxt[NF];
        #pragma unroll
        for (int t = 0; t < 9; ++t) {
            const int sn = (t < 8) ? ((t + 1) * 12 + c) : (c < 11 ? (c + 1) : 0);
            loadB(sn, bnxt);
            const int troff = (t / 3) * HPIN + (t % 3);
            bf16x8 af[4];
            #pragma unroll
            for (int mf = 0; mf < 4; ++mf)
                if (mf < mfc)
                    af[mf] = *(const bf16x8*)&s_a[off + (prow[mf] + troff) * 40 + kg * 8];
            __builtin_amdgcn_s_setprio(1);
            #pragma unroll
            for (int nf = 0; nf < NF; ++nf)
                #pragma unroll
                for (int mf = 0; mf < 4; ++mf)
                    if (mf < mfc)
                        acc[mf][nf] = __builtin_amdgcn_mfma_f32_16x16x32_bf16(
                            af[mf], bcur[nf], acc[mf][nf], 0, 0, 0);
            __builtin_amdgcn_s_setprio(0);
            #pragma unroll
            for (int nf = 0; nf < NF; ++nf) bcur[nf] = bnxt[nf];
        }
    };

    bf16x8 bpipe[NF];
    loadB(0, bpipe);

    if (DBUF) {
        loadG(0); writeL(0);
        __syncthreads();
        int buf = 0;
        for (int c = 0; c < 12; ++c) {
            if (c + 1 < 12) loadG(c + 1);
            compute(c, buf * BUFSZ, bpipe);
            if (c + 1 < 12) writeL((buf ^ 1) * BUFSZ);
            __syncthreads();
            buf ^= 1;
        }
    } else {
        loadG(0);
        for (int c = 0; c < 12; ++c) {
            if (c) __syncthreads();
            writeL(0);
            __syncthreads();
            if (c + 1 < 12) loadG(c + 1);
            compute(c, 0, bpipe);
        }
    }

    #pragma unroll
    for (int nf = 0; nf < NF; ++nf) {
        const int oc = n0 + wn + nf * 16 + l15;
        const float bv = bias[oc];
        #pragma unroll
        for (int mf = 0; mf < 4; ++mf) {
            #pragma unroll
            for (int j = 0; j < 4; ++j) {
                int p_out = wm + mf * 16 + kg * 4 + j;
                if (p_out < M_BLK) {
                    float v = acc[mf][nf][j] + bv;
                    v = v > 0.f ? v : 0.f;
                    int b2 = bb0 + p_out / PIX;
                    int pr2 = p_out % PIX;
                    if (MODE == 0) {
                        int y2 = pr2 / HOUT, x2 = pr2 - y2 * HOUT;
                        size_t d = ((size_t)(b2 * HPOUT + y2 + 1) * HPOUT + (x2 + 1)) * OC_T + oc;
                        out_h[d] = round_bf16(v);
                    } else {
                        out_h[((size_t)b2 * OC_T + oc) * PIX + pr2] = round_bf16(v);
                    }
                }
            }
        }
    }
}

// --- CP=2 conv: 64-ic phases, 6 phases. Row stride 72 shorts (conflict-free).
template<int OC_T, int HOUT, int HPIN, int HPOUT, int STRIDE, int MODE, int NT,
         int NSAMP, int DBUF>
__global__ void __launch_bounds__(256)
conv_mfma6(const short* __restrict__ in_h, const short* __restrict__ wph,
           const float* __restrict__ bias, short* __restrict__ out_h)
{
    constexpr int IC = 384;
    constexpr int NS = 108;
    constexpr int NF = NT / 32;
    constexpr int PIX = HOUT * HOUT;
    constexpr int M_BLK = NSAMP * PIX;
    constexpr int PROWS = NSAMP * HPIN * HPIN;
    constexpr int G = OC_T / NT;
    constexpr int RS = 72;                       // shorts per row (64 + 8 pad)
    constexpr int NU = (PROWS * 4 + 255) / 256;  // 16-short units
    constexpr int BUFSZ = PROWS * RS;
    __shared__ short s_a[(DBUF ? 2 : 1) * BUFSZ];

    const int swz = xcd_swizzle(blockIdx.x, gridDim.x);
    const int mt = swz / G;
    const int g  = swz % G;
    const int n0 = g * NT;
    const int bb0 = mt * NSAMP;

    const int tid = threadIdx.x;
    const int lane = tid & 63;
    const int wid  = tid >> 6;
    const int wm = (wid & 1) * 64;
    const int wn = (wid >> 1) * (NT / 2);
    const int l15 = lane & 15, kg = lane >> 4;

    const int mrows = M_BLK - wm;
    const int mfc = mrows >= 64 ? 4 : (mrows + 15) >> 4;

    size_t usrc[NU]; int udst[NU]; bool uval[NU];
    #pragma unroll
    for (int j = 0; j < NU; ++j) {
        int u = tid + j * 256;
        int row = u >> 2, part = u & 3;
        uval[j] = row < PROWS;
        int rc = uval[j] ? row : 0;
        int sN = rc / (HPIN * HPIN), rr = rc % (HPIN * HPIN);
        usrc[j] = ((size_t)(bb0 + sN) * (HPIN * HPIN) + rr) * IC + part * 16;
        udst[j] = rc * RS + part * 16;
    }

    int prow[4];
    #pragma unroll
    for (int mf = 0; mf < 4; ++mf) {
        int p = wm + mf * 16 + l15;
        int pc = p < M_BLK ? p : M_BLK - 1;
        int sN = pc / PIX, pr = pc % PIX;
        int py = pr / HOUT, px = pr - py * HOUT;
        prow[mf] = sN * (HPIN * HPIN) + py * STRIDE * HPIN + px * STRIDE;
    }

    const short* wb = wph + (size_t)((n0 + wn) >> 4) * (NS * 512) + lane * 8;

    f32x4 acc[4][NF];
    #pragma unroll
    for (int i = 0; i < 4; ++i)
        #pragma unroll
        for (int j = 0; j < NF; ++j)
            acc[i][j] = (f32x4){0.f, 0.f, 0.f, 0.f};

    bf16x8 sreg[NU][2];
    auto loadG = [&](int p) {                    // p = phase (64 ic)
        #pragma unroll
        for (int j = 0; j < NU; ++j) if (uval[j]) {
            const short* src = in_h + usrc[j] + p * 64;
            sreg[j][0] = *(const bf16x8*)src;
            sreg[j][1] = *(const bf16x8*)(src + 8);
        }
    };
    auto writeL = [&](int off) {
        #pragma unroll
        for (int j = 0; j < NU; ++j) if (uval[j]) {
            *(bf16x8*)&s_a[off + udst[j]]     = sreg[j][0];
            *(bf16x8*)&s_a[off + udst[j] + 8] = sreg[j][1];
        }
    };
    auto loadB = [&](int s, bf16x8 (&bh)[NF]) {
        #pragma unroll
        for (int nf = 0; nf < NF; ++nf)
            bh[nf] = *(const bf16x8*)(wb + (size_t)nf * (NS * 512) + (size_t)s * 512);
    };
    // 18 steps per phase: u = ks*9 + t, B step index = t*12 + p*2 + ks
    auto compute = [&](int p, int off, bf16x8 (&bcur)[NF]) {
        bf16x8 bnxt[NF];
        #pragma unroll
        for (int u = 0; u < 18; ++u) {
            const int ks = u / 9, t = u % 9;
            int un = u + 1, sn;
            if (un < 18) sn = (un % 9) * 12 + p * 2 + (un / 9);
            else         sn = (p < 5) ? (p + 1) * 2 : 0;
            loadB(sn, bnxt);
            const int troff = (t / 3) * HPIN + (t % 3);
            bf16x8 af[4];
            #pragma unroll
            for (int mf = 0; mf < 4; ++mf)
                if (mf < mfc)
                    af[mf] = *(const bf16x8*)&s_a[off + (prow[mf] + troff) * RS
                                                  + ks * 32 + kg * 8];
            __builtin_amdgcn_s_setprio(1);
            #pragma unroll
            for (int nf = 0; nf < NF; ++nf)
                #pragma unroll
                for (int mf = 0; mf < 4; ++mf)
                    if (mf < mfc)
                        acc[mf][nf] = __builtin_amdgcn_mfma_f32_16x16x32_bf16(
                            af[mf], bcur[nf], acc[mf][nf], 0, 0, 0);
            __builtin_amdgcn_s_setprio(0);
            #pragma unroll
            for (int nf = 0; nf < NF; ++nf) bcur[nf] = bnxt[nf];
        }
    };

    bf16x8 bpipe[NF];
    loadB(0, bpipe);

    if (DBUF) {
        loadG(0); writeL(0);
        __syncthreads();
        int buf = 0;
        for (int p = 0; p < 6; ++p) {
            if (p + 1 < 6) loadG(p + 1);
            compute(p, buf * BUFSZ, bpipe);
            if (p + 1 < 6) writeL((buf ^ 1) * BUFSZ);
            __syncthreads();
            buf ^= 1;
        }
    } else {
        loadG(0);
        for (int p = 0; p < 6; ++p) {
            if (p) __syncthreads();
            writeL(0);
            __syncthreads();
            if (p + 1 < 6) loadG(p + 1);
            compute(p, 0, bpipe);
        }
    }

    #pragma unroll
    for (int nf = 0; nf < NF; ++nf) {
        const int oc = n0 + wn + nf * 16 + l15;
        const float bv = bias[oc];
        #pragma unroll
        for (int mf = 0; mf < 4; ++mf) {
            #pragma unroll
            for (int j = 0; j < 4; ++j) {
                int p_out = wm + mf * 16 + kg * 4 + j;
                if (p_out < M_BLK) {
                    float v = acc[mf][nf][j] + bv;
                    v = v > 0.f ? v : 0.f;
                    int b2 = bb0 + p_out / PIX;
                    int pr2 = p_out % PIX;
                    if (MODE == 0) {
                        int y2 = pr2 / HOUT, x2 = pr2 - y2 * HOUT;
                        size_t d = ((size_t)(b2 * HPOUT + y2 + 1) * HPOUT + (x2 + 1)) * OC_T + oc;
                        out_h[d] = round_bf16(v);
                    } else {
                        out_h[((size_t)b2 * OC_T + oc) * PIX + pr2] = round_bf16(v);
                    }
                }
            }
        }
    }
}

// Split-K bf16 MFMA GEMM for conv4, single-product. KS=25 -> 16 k-steps.
template<int KS>
__global__ void __launch_bounds__(256)
gemm4_mfma3(const short* __restrict__ Ah, const short* __restrict__ wph,
            float* __restrict__ Cpart, int M)
{
    constexpr int NS4 = 400;
    constexpr int NSTEP = NS4 / KS;             // 16
    __shared__ short s_a[2][128 * 40];
    const int tid = threadIdx.x;
    const int nM = (M + 127) / 128;
    const int ks = blockIdx.x / (nM * 4);
    const int rb = blockIdx.x % (nM * 4);
    const int M0 = (rb / 4) * 128;
    const int n0 = (rb % 4) * 128;

    const int lane = tid & 63;
    const int wid  = tid >> 6;
    const int wm = (wid & 1) * 64;
    const int wn = (wid >> 1) * 64;
    const int l15 = lane & 15, kg = lane >> 4;

    const int arow = tid >> 1, ahf = tid & 1;
    int P = M0 + arow; if (P >= M) P = M - 1;
    const short* abase = Ah + (size_t)P * 12800 + ahf * 16;
    const int adst = arow * 40 + ahf * 16;

    const short* wbh = wph + (size_t)((n0 + wn) >> 4) * (NS4 * 512) + lane * 8;

    f32x4 acc[4][4];
    #pragma unroll
    for (int i = 0; i < 4; ++i)
        #pragma unroll
        for (int j = 0; j < 4; ++j)
            acc[i][j] = (f32x4){0.f, 0.f, 0.f, 0.f};

    auto stageA = [&](int j, int buf) {
        const short* src = abase + (size_t)(ks * NSTEP + j) * 32;
        *(bf16x8*)&s_a[buf][adst]     = *(const bf16x8*)src;
        *(bf16x8*)&s_a[buf][adst + 8] = *(const bf16x8*)(src + 8);
    };
    auto loadB = [&](int j, bf16x8 (&bh)[4]) {
        #pragma unroll
        for (int nf = 0; nf < 4; ++nf)
            bh[nf] = *(const bf16x8*)(wbh + (size_t)nf * (NS4 * 512)
                                      + (size_t)(ks * NSTEP + j) * 512);
    };
    auto compute = [&](const bf16x8 (&bh)[4], int buf) {
        bf16x8 af[4];
        #pragma unroll
        for (int mf = 0; mf < 4; ++mf)
            af[mf] = *(const bf16x8*)&s_a[buf][(wm + mf * 16 + l15) * 40 + kg * 8];
        __builtin_amdgcn_s_setprio(1);
        #pragma unroll
        for (int nf = 0; nf < 4; ++nf)
            #pragma unroll
            for (int mf = 0; mf < 4; ++mf)
                acc[mf][nf] = __builtin_amdgcn_mfma_f32_16x16x32_bf16(
                    af[mf], bh[nf], acc[mf][nf], 0, 0, 0);
        __builtin_amdgcn_s_setprio(0);
    };

    bf16x8 bhA[4], bhB[4];
    stageA(0, 0);
    loadB(0, bhA);
    __syncthreads();
    for (int jp = 0; jp < NSTEP; jp += 2) {
        stageA(jp + 1, 1);
        loadB(jp + 1, bhB);
        compute(bhA, 0);
        __syncthreads();
        if (jp + 2 < NSTEP) { stageA(jp + 2, 0); loadB(jp + 2, bhA); }
        compute(bhB, 1);
        __syncthreads();
    }

    float* cp = Cpart + (size_t)ks * M * 512;
    #pragma unroll
    for (int nf = 0; nf < 4; ++nf) {
        const int n = n0 + wn + nf * 16 + l15;
        #pragma unroll
        for (int mf = 0; mf < 4; ++mf) {
            #pragma unroll
            for (int j = 0; j < 4; ++j) {
                int m = M0 + wm + mf * 16 + kg * 4 + j;
                if (m < M) cp[(size_t)m * 512 + n] = acc[mf][nf][j];
            }
        }
    }
}

template<int KS>
__global__ void splitk_reduce_relu(const float* __restrict__ Cpart,
                                   const float* __restrict__ bias,
                                   float* __restrict__ out, int M, int N)
{
    int idx = blockIdx.x * blockDim.x + threadIdx.x;
    if (idx >= M * N) return;
    int oc = idx % N;
    float s = bias[oc];
    #pragma unroll
    for (int ks = 0; ks < KS; ++ks)
        s += Cpart[(size_t)ks * M * N + idx];
    out[idx] = s > 0.f ? s : 0.f;
}

__global__ void linear_naive(const float* __restrict__ x, const float* __restrict__ Wl,
                             const float* __restrict__ bl,
                             float* __restrict__ out, int total)
{
    int idx = blockIdx.x * blockDim.x + threadIdx.x;
    if (idx >= total) return;
    int b = idx / 10, j = idx - b * 10;
    const float* xb = x  + (size_t)b * 512;
    const float* wj = Wl + (size_t)j * 512;
    float s = bl[j];
    for (int k = 0; k < 512; ++k)
        s += xb[k] * wj[k];
    out[idx] = s;
}

extern "C" void kernel_launch(void* const* d_in, const int* in_sizes, int n_in,
                              void* d_out, int out_size, void* d_ws, size_t ws_size,
                              hipStream_t stream)
{
    const float* A  = (const float*)d_in[0];
    const float* S  = (const float*)d_in[1];
    const float* W1 = (const float*)d_in[2];
    const float* b1 = (const float*)d_in[3];
    const float* W2 = (const float*)d_in[4];
    const float* b2 = (const float*)d_in[5];
    const float* W3 = (const float*)d_in[6];
    const float* b3 = (const float*)d_in[7];
    const float* W4 = (const float*)d_in[8];
    const float* b4 = (const float*)d_in[9];
    const float* Wl = (const float*)d_in[10];
    const float* bl = (const float*)d_in[11];
    float* outp = (float*)d_out;
    char* base = (char*)d_ws;

    const int Btot = 512;
    constexpr int KS = 25;

    const size_t W12N = (size_t)384 * 3456;
    const size_t W3N  = (size_t)512 * 3456;
    const size_t W4N  = (size_t)512 * 12800;
    size_t off = 0;
    short* w1h = (short*)(base + off); off += W12N * 2;
    short* w2h = (short*)(base + off); off += W12N * 2;
    short* w3h = (short*)(base + off); off += W3N * 2;
    short* w4h = (short*)(base + off); off += W4N * 2;
    const size_t wreg = off;

    const size_t PS = 337664;
    int Bc = 512;
    while (Bc > 8 && wreg + (size_t)Bc * PS > ws_size) Bc >>= 1;

    pack_w_frag_h8<<<(int)((W12N / 8 + 255) / 256), 256, 0, stream>>>(W1, w1h, (int)(W12N / 8));
    pack_w_frag_h8<<<(int)((W12N / 8 + 255) / 256), 256, 0, stream>>>(W2, w2h, (int)(W12N / 8));
    pack_w_frag_h8<<<(int)((W3N  / 8 + 255) / 256), 256, 0, stream>>>(W3, w3h, (int)(W3N / 8));
    pack_w4_frag_h8<<<(int)((W4N / 8 + 255) / 256), 256, 0, stream>>>(W4, w4h, (int)(W4N / 8));

    size_t o2 = wreg;
    short* x0h = (short*)(base + o2); o2 += (size_t)Bc * 110592;
    short* x1h = (short*)(base + o2); o2 += (size_t)Bc * 110592;
    short* x2h = (short*)(base + o2); o2 += (size_t)Bc * 37632;
    short* x3h = (short*)(base + o2); o2 += (size_t)Bc * 25600;
    float* cp  = (float*)(base + o2); o2 += (size_t)Bc * (KS * 512 * 4);
    float* x4  = (float*)(base + o2);

    // border-only zeroing of padded planes (interiors rewritten every launch)
    {
        int t0 = Bc * 44 * 48;
        zero_border<12, 384><<<(t0 + 255) / 256, 256, 0, stream>>>(x0h, Bc);
        zero_border<12, 384><<<(t0 + 255) / 256, 256, 0, stream>>>(x1h, Bc);
        int t2 = Bc * 24 * 48;
        zero_border<7, 384><<<(t2 + 255) / 256, 256, 0, stream>>>(x2h, Bc);
    }

    for (int b0 = 0; b0 < Btot; b0 += Bc) {
        einsum_pack3<<<dim3(Bc), 384, 0, stream>>>(
            A + (size_t)b0 * 2048, S + (size_t)b0 * 4800, x0h);

        // conv1: CP=2 single-buf (20.7 KB), 6 phases, grid Bc*3
        conv_mfma6<384, 10, 12, 12, 1, 0, 128, 1, 0>
            <<<dim3(Bc * 3), 256, 0, stream>>>(x0h, w1h, b1, x1h);

        // conv2: 4 samples/block, NT=96 (CP=1, single-buf 46 KB)
        conv_mfma5<384, 5, 12, 7, 2, 0, 96, 4, 0>
            <<<dim3((Bc / 4) * 4), 256, 0, stream>>>(x1h, w2h, b2, x2h);

        // conv3: CP=2 dbuf (56.4 KB), 6 phases, NT=128, NCHW out
        conv_mfma6<512, 5, 7, 1, 1, 1, 128, 4, 1>
            <<<dim3((Bc / 4) * 4), 256, 0, stream>>>(x2h, w3h, b3, x3h);

        int nM = (Bc + 127) / 128;
        gemm4_mfma3<KS><<<dim3(KS * nM * 4), 256, 0, stream>>>(
            x3h, w4h, cp, Bc);
        int tr = Bc * 512;
        splitk_reduce_relu<KS><<<(tr + 255) / 256, 256, 0, stream>>>(
            cp, b4, x4, Bc, 512);

        int t5 = Bc * 10;
        linear_naive<<<(t5 + 255) / 256, 256, 0, stream>>>(
            x4, Wl, bl, outp + (size_t)b0 * 10, t5);
    }
}